// Round 2
// baseline (16817.712 us; speedup 1.0000x reference)
//
#include <hip/hip_runtime.h>

#define DI __device__ __forceinline__

constexpr int B = 32, L = 100, T = 50;
constexpr int VS = 20000;
constexpr int HR = 250, HD = 500;
constexpr int INE = 460;

// ---- workspace byte offsets ----
constexpr size_t O_X      = 0;            // x [B][L][460] f32
constexpr size_t O_SX     = 5888000;      // sent_x [T][B][400] f32
constexpr size_t O_WIHFT  = 8448000;      // enc_Wih_f^T [460][1000] f32
constexpr size_t O_WIHBT  = 10288000;
constexpr size_t O_WDECT  = 12128000;     // dec_Wih^T [400][2000] f32
constexpr size_t O_W4ENC  = 15328000;     // [2dir][250u][250k][4g] f32
constexpr size_t O_W4DEC  = 17328000;     // [500u][500k][4g] f32
constexpr size_t O_XWF    = 21328000;     // [100][1000][32] f64
constexpr size_t O_XWB    = 46928000;
constexpr size_t O_XWD    = 72528000;     // [50][2000][32] f64
constexpr size_t O_EOT    = 98128000;     // enc_outT [100][500][32] f64
constexpr size_t O_EOB    = 110928000;    // enc_outB [32][100][500] f64
constexpr size_t O_HENC   = 123728000;    // [2ph][2dir][250][32] f64
constexpr size_t O_CENC   = 123984000;    // [2dir][250][32] f64
constexpr size_t O_HDEC   = 124112000;    // [2ph][500][32] f64
constexpr size_t O_CDEC   = 124368000;    // [500][32] f64
constexpr size_t O_ATTN   = 124496000;    // [32][50][100] f32
constexpr size_t O_LAM    = 125136000;    // [1600] f32
constexpr size_t O_LS1    = 125142400;    // [1600] f32
constexpr size_t O_WIDX   = 125148800;    // [1600] int (attn-pred word id)
constexpr size_t O_OUTS   = 125155200;    // outs f32 [1600][512]
// end 128,432,000 bytes

// output element offsets (f32)
constexpr size_t OUT_HT  = 32000000;
constexpr size_t OUT_CT  = 32016000;
constexpr size_t OUT_AP  = 32032000;
constexpr size_t OUT_DP  = 32512000;

DI double dsig(double x) { return 1.0 / (1.0 + exp(-x)); }

// ---------------- prep kernels ----------------

__global__ void k_embed_x(const float* Es, const float* Ef, const float* Ep, const float* En,
                          const int* value, const int* field, const int* ppos, const int* pneg,
                          float* x) {
    int i = blockIdx.x * 256 + threadIdx.x;
    if (i >= B * L * INE) return;
    int j = i % INE, bl = i / INE;
    float v;
    if (j < 400)      v = Es[(size_t)value[bl] * 400 + j];
    else if (j < 450) v = Ef[(size_t)field[bl] * 50 + (j - 400)];
    else if (j < 455) v = Ep[(size_t)ppos[bl] * 5 + (j - 450)];
    else              v = En[(size_t)pneg[bl] * 5 + (j - 455)];
    x[i] = v;
}

__global__ void k_embed_sent(const float* Es, const int* sent, float* sx) {
    int i = blockIdx.x * 256 + threadIdx.x;
    if (i >= T * B * 400) return;
    int k = i % 400, tb = i / 400;
    int b = tb % B, t = tb / B;
    sx[i] = Es[(size_t)sent[b * T + t] * 400 + k];
}

__global__ void k_transpose(float* dst, const float* src, int K, int G) {
    int i = blockIdx.x * 256 + threadIdx.x;
    if (i >= K * G) return;
    int g = i % G, k = i / G;
    dst[i] = src[(size_t)g * K + k];
}

__global__ void k_pack4(float* dst, const float* src, int U, int Kh) {
    int i = blockIdx.x * 256 + threadIdx.x;
    if (i >= U * Kh * 4) return;
    int g = i & 3, rest = i >> 2;
    int k = rest % Kh, u = rest / Kh;
    dst[i] = src[((size_t)(g * U + u)) * Kh + k];
}

__global__ void k_zerod(double* p, int n) {
    int i = blockIdx.x * 256 + threadIdx.x;
    if (i < n) p[i] = 0.0;
}

// out[t][g][b] = bias[g] + sum_k xs[b,t,k] * Wt[k][g]   (f64 accumulate)
__global__ __launch_bounds__(256) void k_gemm_xw(double* out, const float* xs, int bstride, int tstride,
                                                 const float* Wt, const float* bias, int K, int G) {
    __shared__ float xls[460 * 33];
    int t = blockIdx.x;
    int g = blockIdx.y * 256 + threadIdx.x;
    bool act = g < G;
    for (int i = threadIdx.x; i < 32 * K; i += 256) {
        int b = i / K, k = i - b * K;
        xls[k * 33 + b] = xs[(size_t)b * bstride + (size_t)t * tstride + k];
    }
    __syncthreads();
    double acc[32];
    double bs = act ? (double)bias[g] : 0.0;
#pragma unroll
    for (int b = 0; b < 32; ++b) acc[b] = bs;
    for (int k = 0; k < K; ++k) {
        double w = act ? (double)Wt[(size_t)k * G + g] : 0.0;
        const float* xr = &xls[k * 33];
#pragma unroll
        for (int b = 0; b < 32; ++b) acc[b] += w * (double)xr[b];
    }
    if (act) {
        double* op = out + ((size_t)t * G + g) * 32;
#pragma unroll
        for (int b = 0; b < 32; ++b) op[b] = acc[b];
    }
}

// ---------------- encoder ----------------

__global__ void k_enc_step(double* h_enc, double* c_enc, double* eoT,
                           const double* xwF, const double* xwB, const float* w4enc, int s) {
    int gt = blockIdx.x * 256 + threadIdx.x;
    if (gt >= 16000) return;
    int dir = gt / 8000, r = gt - dir * 8000;
    int u = r >> 5, b = r & 31;
    int ph = s & 1;
    int tin = dir ? (L - 1 - s) : s;
    const double* xw = dir ? xwB : xwF;
    double zi = xw[((size_t)tin * 1000 + 0 * HR + u) * 32 + b];
    double zf = xw[((size_t)tin * 1000 + 1 * HR + u) * 32 + b];
    double zg = xw[((size_t)tin * 1000 + 2 * HR + u) * 32 + b];
    double zo = xw[((size_t)tin * 1000 + 3 * HR + u) * 32 + b];
    const float4* W4 = (const float4*)w4enc + ((size_t)(dir * 250 + u)) * 250;
    const double* hp = h_enc + ph * 16000 + dir * 8000;
    for (int k = 0; k < 250; ++k) {
        double hv = hp[k * 32 + b];
        float4 w = W4[k];
        zi += (double)w.x * hv; zf += (double)w.y * hv;
        zg += (double)w.z * hv; zo += (double)w.w * hv;
    }
    double co = c_enc[dir * 8000 + u * 32 + b];
    double cn = dsig(zf) * co + dsig(zi) * tanh(zg);
    double hn = dsig(zo) * tanh(cn);
    c_enc[dir * 8000 + u * 32 + b] = cn;
    h_enc[(ph ^ 1) * 16000 + dir * 8000 + u * 32 + b] = hn;
    eoT[((size_t)tin * 500 + dir * 250 + u) * 32 + b] = hn;
}

__global__ void k_enc_tr(double* eoB, const double* eoT) {
    int i = blockIdx.x * 256 + threadIdx.x;
    if (i >= B * L * 500) return;
    int e = i % 500, bl = i / 500;
    int l = bl % 100, b = bl / 100;
    eoB[i] = eoT[((size_t)l * 500 + e) * 32 + b];
}

// replicate torch .view on [2,B,250] -> [B,500]
__global__ void k_scramble(double* hdec, double* cdec, const double* henc, const double* cenc) {
    int gt = blockIdx.x * 256 + threadIdx.x;
    if (gt >= 16000) return;
    int bb = gt / 500, j = gt - bb * 500;
    int d = gt / 8000, rem = gt - d * 8000;
    int bs = rem / 250, us = rem - bs * 250;
    hdec[j * 32 + bb] = henc[d * 8000 + us * 32 + bs];   // henc = phase 0 base
    cdec[j * 32 + bb] = cenc[d * 8000 + us * 32 + bs];
}

// ---------------- decoder ----------------

__global__ void k_dec_cell(double* hdec, double* cdec, const double* xwD, const float* w4dec, int t) {
    int gt = blockIdx.x * 256 + threadIdx.x;
    if (gt >= 16000) return;
    int u = gt >> 5, b = gt & 31;
    int ph = t & 1;
    double zi = xwD[((size_t)t * 2000 + 0 * HD + u) * 32 + b];
    double zf = xwD[((size_t)t * 2000 + 1 * HD + u) * 32 + b];
    double zg = xwD[((size_t)t * 2000 + 2 * HD + u) * 32 + b];
    double zo = xwD[((size_t)t * 2000 + 3 * HD + u) * 32 + b];
    const float4* W4 = (const float4*)w4dec + (size_t)u * 500;
    const double* hp = hdec + ph * 16000;
    for (int k = 0; k < 500; ++k) {
        double hv = hp[k * 32 + b];
        float4 w = W4[k];
        zi += (double)w.x * hv; zf += (double)w.y * hv;
        zg += (double)w.z * hv; zo += (double)w.w * hv;
    }
    double co = cdec[u * 32 + b];
    double cn = dsig(zf) * co + dsig(zi) * tanh(zg);
    double hn = dsig(zo) * tanh(cn);
    cdec[u * 32 + b] = cn;
    hdec[(ph ^ 1) * 16000 + u * 32 + b] = hn;
}

__global__ __launch_bounds__(256) void k_dec_attn(
        const double* hdec, const float* x, const double* eoB, const float* sx,
        const float* Wd, const float* Wz, const float* Wo,
        const float* b_out, const float* w_l, const float* b_l, const int* value,
        float* attn_ws, float* lam_ws, int* widx, float* outs32, int t) {
    int b = blockIdx.x, tid = threadIdx.x;
    int m = b * T + t;
    int ph1 = (t & 1) ^ 1;
    __shared__ double hL[500], hwd[500], hzL[60], sdL[100], szL[100], aL[100], ctxL[500];
    __shared__ double red[256];
    __shared__ int ri[256];

    for (int k = tid; k < 500; k += 256) hL[k] = hdec[ph1 * 16000 + k * 32 + b];
    __syncthreads();
    for (int e = tid; e < 500; e += 256) {
        double a0 = 0.0, a1 = 0.0;
        for (int d = 0; d < 500; d += 2) {
            a0 += hL[d]     * (double)Wd[(size_t)d * 500 + e];
            a1 += hL[d + 1] * (double)Wd[(size_t)(d + 1) * 500 + e];
        }
        hwd[e] = a0 + a1;
    }
    for (int f = tid; f < 60; f += 256) {
        double a0 = 0.0, a1 = 0.0;
        for (int d = 0; d < 500; d += 2) {
            a0 += hL[d]     * (double)Wz[(size_t)d * 60 + f];
            a1 += hL[d + 1] * (double)Wz[(size_t)(d + 1) * 60 + f];
        }
        hzL[f] = a0 + a1;
    }
    __syncthreads();
    if (tid < 100) {
        const double* er = eoB + ((size_t)b * 100 + tid) * 500;
        double s0 = 0.0, s1 = 0.0;
        for (int e = 0; e < 500; e += 2) { s0 += hwd[e] * er[e]; s1 += hwd[e + 1] * er[e + 1]; }
        sdL[tid] = s0 + s1;
        const float* zr = x + ((size_t)b * 100 + tid) * 460 + 400;
        double sz = 0.0;
        for (int f = 0; f < 60; ++f) sz += hzL[f] * (double)zr[f];
        szL[tid] = sz;
    }
    __syncthreads();
    // softmax(s_d) * softmax(s_z), renorm by (sum + 1e-3)
    red[tid] = (tid < 100) ? sdL[tid] : -1e300; __syncthreads();
    for (int o = 128; o > 0; o >>= 1) { if (tid < o) red[tid] = fmax(red[tid], red[tid + o]); __syncthreads(); }
    double md = red[0]; __syncthreads();
    red[tid] = (tid < 100) ? exp(sdL[tid] - md) : 0.0; __syncthreads();
    for (int o = 128; o > 0; o >>= 1) { if (tid < o) red[tid] += red[tid + o]; __syncthreads(); }
    double Sd = red[0]; __syncthreads();
    red[tid] = (tid < 100) ? szL[tid] : -1e300; __syncthreads();
    for (int o = 128; o > 0; o >>= 1) { if (tid < o) red[tid] = fmax(red[tid], red[tid + o]); __syncthreads(); }
    double mz = red[0]; __syncthreads();
    red[tid] = (tid < 100) ? exp(szL[tid] - mz) : 0.0; __syncthreads();
    for (int o = 128; o > 0; o >>= 1) { if (tid < o) red[tid] += red[tid + o]; __syncthreads(); }
    double Sz = red[0]; __syncthreads();
    if (tid < 100) aL[tid] = (exp(sdL[tid] - md) / Sd) * (exp(szL[tid] - mz) / Sz);
    __syncthreads();
    red[tid] = (tid < 100) ? aL[tid] : 0.0; __syncthreads();
    for (int o = 128; o > 0; o >>= 1) { if (tid < o) red[tid] += red[tid + o]; __syncthreads(); }
    double Sa = red[0]; __syncthreads();
    if (tid < 100) {
        double av = aL[tid] / (Sa + 1e-3);
        aL[tid] = av;
        attn_ws[(size_t)m * 100 + tid] = (float)av;
    }
    __syncthreads();
    // f64 argmax of attention (first-max), resolve word id
    red[tid] = (tid < 100) ? aL[tid] : -1e300;
    ri[tid]  = (tid < 100) ? tid : 0x7fffffff;
    __syncthreads();
    for (int o = 128; o > 0; o >>= 1) {
        if (tid < o) {
            if (red[tid + o] > red[tid] || (red[tid + o] == red[tid] && ri[tid + o] < ri[tid])) {
                red[tid] = red[tid + o]; ri[tid] = ri[tid + o];
            }
        }
        __syncthreads();
    }
    if (tid == 0) widx[m] = value[b * 100 + ri[0]];
    __syncthreads();
    for (int e = tid; e < 500; e += 256) {
        double acc = 0.0;
        for (int l = 0; l < 100; ++l) acc += aL[l] * eoB[((size_t)b * 100 + l) * 500 + e];
        ctxL[e] = acc;
    }
    __syncthreads();
    for (int e = tid; e < 512; e += 256) {
        if (e < 500) {
            double a0 = (double)b_out[e], a1 = 0.0;
            for (int j = 0; j < 500; j += 2) {
                a0 += hL[j]     * (double)Wo[(size_t)j * 500 + e];
                a1 += hL[j + 1] * (double)Wo[(size_t)(j + 1) * 500 + e];
            }
            for (int j = 0; j < 500; j += 2) {
                a0 += ctxL[j]     * (double)Wo[(size_t)(500 + j) * 500 + e];
                a1 += ctxL[j + 1] * (double)Wo[(size_t)(501 + j) * 500 + e];
            }
            outs32[(size_t)m * 512 + e] = (float)tanh(a0 + a1);
        } else {
            outs32[(size_t)m * 512 + e] = 0.f;
        }
    }
    // lambda
    double part = 0.0;
    for (int j = tid; j < 1400; j += 256) {
        double val = (j < 500) ? hL[j] : (j < 1000 ? ctxL[j - 500]
                    : (double)sx[((size_t)t * B + b) * 400 + (j - 1000)]);
        part += val * (double)w_l[j];
    }
    red[tid] = part; __syncthreads();
    for (int o = 128; o > 0; o >>= 1) { if (tid < o) red[tid] += red[tid + o]; __syncthreads(); }
    if (tid == 0) lam_ws[m] = (float)dsig(red[0] + (double)b_l[0]);
}

__global__ void k_hTcT(float* out, const double* hdec, const double* cdec) {
    int i = blockIdx.x * 256 + threadIdx.x;
    if (i >= 16000) return;
    int b = i / 500, u = i - b * 500;
    out[OUT_HT + i] = (float)hdec[u * 32 + b];   // phase-0 base holds h_T
    out[OUT_CT + i] = (float)cdec[u * 32 + b];
}

// ---------------- logits GEMM (f32 vector): d_out = outs @ W_lin^T + b_lin ----------------

__global__ __launch_bounds__(256) void k_gemm_logits_f32(const float* outs32, const float* W_lin,
                                                         const float* b_lin, float* d_out) {
    __shared__ float As[16][68], Bs[16][68];
    int n0 = blockIdx.x * 64, m0 = blockIdx.y * 64;
    int tid = threadIdx.x;
    int ty = tid >> 4, tx = tid & 15;       // ty,tx in [0,16)
    int lr = tid >> 2, lc = tid & 3;        // stager: row lr in [0,64), k-quad lc
    float acc[4][4];
#pragma unroll
    for (int i = 0; i < 4; ++i)
#pragma unroll
        for (int j = 0; j < 4; ++j) acc[i][j] = 0.f;

    for (int k0 = 0; k0 < 512; k0 += 16) {
        int k4 = k0 + lc * 4;
        float4 av = *(const float4*)(outs32 + (size_t)(m0 + lr) * 512 + k4);
        int n = n0 + lr;
        float4 bv;
        if (n < VS && k4 < 500) bv = *(const float4*)(W_lin + (size_t)n * 500 + k4);
        else bv = make_float4(0.f, 0.f, 0.f, 0.f);
        __syncthreads();
        As[lc * 4 + 0][lr] = av.x; As[lc * 4 + 1][lr] = av.y;
        As[lc * 4 + 2][lr] = av.z; As[lc * 4 + 3][lr] = av.w;
        Bs[lc * 4 + 0][lr] = bv.x; Bs[lc * 4 + 1][lr] = bv.y;
        Bs[lc * 4 + 2][lr] = bv.z; Bs[lc * 4 + 3][lr] = bv.w;
        __syncthreads();
#pragma unroll
        for (int kk = 0; kk < 16; ++kk) {
            float4 a4 = *(const float4*)&As[kk][ty * 4];
            float4 b4 = *(const float4*)&Bs[kk][tx * 4];
            float ar[4] = {a4.x, a4.y, a4.z, a4.w};
            float br[4] = {b4.x, b4.y, b4.z, b4.w};
#pragma unroll
            for (int i = 0; i < 4; ++i)
#pragma unroll
                for (int j = 0; j < 4; ++j) acc[i][j] += ar[i] * br[j];
        }
    }
#pragma unroll
    for (int j = 0; j < 4; ++j) {
        int n = n0 + tx * 4 + j;
        if (n < VS) {
            float bl = b_lin[n];
#pragma unroll
            for (int i = 0; i < 4; ++i) {
                int mm = m0 + ty * 4 + i;
                d_out[(size_t)mm * VS + n] = acc[i][j] + bl;
            }
        }
    }
}

// ---------------- softmax passes ----------------

__global__ void k_red1(const float* d_out, float* LS1) {
    int m = blockIdx.x, tid = threadIdx.x;
    const float* row = d_out + (size_t)m * VS;
    __shared__ float red[256];
    float lm = -3e38f;
    for (int v = tid; v < VS; v += 256) lm = fmaxf(lm, row[v]);
    red[tid] = lm; __syncthreads();
    for (int o = 128; o > 0; o >>= 1) { if (tid < o) red[tid] = fmaxf(red[tid], red[tid + o]); __syncthreads(); }
    float m1 = red[0]; __syncthreads();
    float ls = 0.f;
    for (int v = tid; v < VS; v += 256) ls += expf(row[v] - m1);
    red[tid] = ls; __syncthreads();
    for (int o = 128; o > 0; o >>= 1) { if (tid < o) red[tid] += red[tid + o]; __syncthreads(); }
    if (tid == 0) LS1[m] = m1 + logf(red[0]);
}

// mix = lam * p_lex + (1-lam) * (logit - ls1), in place on d_out
__global__ __launch_bounds__(256) void k_plexmix(float* d_out, const float* attn_ws, const float* align_prob,
                                                 const float* lam_ws, const float* LS1) {
    int b = blockIdx.y, v0 = blockIdx.x * 64, tid = threadIdx.x;
    __shared__ float attn_s[50 * 100];
    __shared__ float al[100 * 64];
    for (int i = tid; i < 5000; i += 256) attn_s[i] = attn_ws[(size_t)b * 5000 + i];
    for (int i = tid; i < 6400; i += 256) {
        int l = i >> 6, j = i & 63;
        int v = v0 + j;
        al[i] = (v < VS) ? align_prob[((size_t)b * 100 + l) * VS + v] : 0.f;
    }
    __syncthreads();
    for (int idx = tid; idx < 50 * 64; idx += 256) {
        int t = idx >> 6, j = idx & 63;
        int v = v0 + j;
        if (v < VS) {
            float acc = 0.f;
            for (int l = 0; l < 100; ++l) acc += attn_s[t * 100 + l] * al[l * 64 + j];
            int m = b * T + t;
            size_t p = (size_t)m * VS + v;
            float lamv = lam_ws[m];
            d_out[p] = lamv * acc + (1.f - lamv) * (d_out[p] - LS1[m]);
        }
    }
}

// log_softmax over mix (in place) + decoder_pred gather
__global__ void k_final2(float* d_out, const float* E_target) {
    int m = blockIdx.x, tid = threadIdx.x;
    float* row = d_out + (size_t)m * VS;
    __shared__ float sm[256], ss[256], sbv[256];
    __shared__ int sbi[256];
    float rm = -3e38f, rs = 0.f, bv = -3e38f; int bi = 0;
    for (int v = tid; v < VS; v += 256) {
        float xv = row[v];
        if (xv > bv) { bv = xv; bi = v; }
        if (xv > rm) { rs = rs * expf(rm - xv) + 1.f; rm = xv; }
        else rs += expf(xv - rm);
    }
    sm[tid] = rm; ss[tid] = rs; sbv[tid] = bv; sbi[tid] = bi;
    __syncthreads();
    for (int o = 128; o > 0; o >>= 1) {
        if (tid < o) {
            float m1 = sm[tid], m2 = sm[tid + o];
            float M = fmaxf(m1, m2);
            ss[tid] = ss[tid] * expf(m1 - M) + ss[tid + o] * expf(m2 - M);
            sm[tid] = M;
            if (sbv[tid + o] > sbv[tid] || (sbv[tid + o] == sbv[tid] && sbi[tid + o] < sbi[tid])) {
                sbv[tid] = sbv[tid + o]; sbi[tid] = sbi[tid + o];
            }
        }
        __syncthreads();
    }
    float ls2 = sm[0] + logf(ss[0]);
    int amax = sbi[0];
    for (int v = tid; v < VS; v += 256) row[v] -= ls2;
    for (int j = tid; j < 300; j += 256)
        d_out[OUT_DP + (size_t)m * 300 + j] = E_target[(size_t)amax * 300 + j];
}

__global__ void k_attnpred2(const int* widx, const float* E_target, float* d_out) {
    int i = blockIdx.x * 256 + threadIdx.x;
    if (i >= 1600 * 300) return;
    int m = i / 300, j = i - m * 300;
    d_out[OUT_AP + i] = E_target[(size_t)widx[m] * 300 + j];
}

// ---------------- launch ----------------

extern "C" void kernel_launch(void* const* d_in, const int* in_sizes, int n_in,
                              void* d_out_v, int out_size, void* d_ws, size_t ws_size,
                              hipStream_t stream) {
    const float* align_prob = (const float*)d_in[1];
    const float* E_sent     = (const float*)d_in[2];
    const float* E_field    = (const float*)d_in[3];
    const float* E_ppos     = (const float*)d_in[4];
    const float* E_pneg     = (const float*)d_in[5];
    const float* E_target   = (const float*)d_in[6];
    const float* enc_Wih_f  = (const float*)d_in[7];
    const float* enc_Whh_f  = (const float*)d_in[8];
    const float* enc_b_f    = (const float*)d_in[9];
    const float* enc_Wih_b  = (const float*)d_in[10];
    const float* enc_Whh_b  = (const float*)d_in[11];
    const float* enc_b_b    = (const float*)d_in[12];
    const float* dec_Wih    = (const float*)d_in[13];
    const float* dec_Whh    = (const float*)d_in[14];
    const float* dec_b      = (const float*)d_in[15];
    const float* W_d        = (const float*)d_in[16];
    const float* W_z        = (const float*)d_in[17];
    const float* W_out      = (const float*)d_in[18];
    const float* b_out      = (const float*)d_in[19];
    const float* w_l        = (const float*)d_in[20];
    const float* b_l        = (const float*)d_in[21];
    const float* W_lin      = (const float*)d_in[22];
    const float* b_lin      = (const float*)d_in[23];
    const int* sent  = (const int*)d_in[24];
    const int* value = (const int*)d_in[25];
    const int* field = (const int*)d_in[26];
    const int* ppos  = (const int*)d_in[27];
    const int* pneg  = (const int*)d_in[28];

    char* ws = (char*)d_ws;
    float*  x      = (float*)(ws + O_X);
    float*  sx     = (float*)(ws + O_SX);
    float*  WihfT  = (float*)(ws + O_WIHFT);
    float*  WihbT  = (float*)(ws + O_WIHBT);
    float*  WdecT  = (float*)(ws + O_WDECT);
    float*  w4enc  = (float*)(ws + O_W4ENC);
    float*  w4dec  = (float*)(ws + O_W4DEC);
    double* xwF    = (double*)(ws + O_XWF);
    double* xwB    = (double*)(ws + O_XWB);
    double* xwD    = (double*)(ws + O_XWD);
    double* eoT    = (double*)(ws + O_EOT);
    double* eoB    = (double*)(ws + O_EOB);
    double* h_enc  = (double*)(ws + O_HENC);
    double* c_enc  = (double*)(ws + O_CENC);
    double* hdec   = (double*)(ws + O_HDEC);
    double* cdec   = (double*)(ws + O_CDEC);
    float*  attn_ws= (float*)(ws + O_ATTN);
    float*  lam_ws = (float*)(ws + O_LAM);
    float*  LS1    = (float*)(ws + O_LS1);
    int*    widx   = (int*)(ws + O_WIDX);
    float*  outs32 = (float*)(ws + O_OUTS);
    float* out = (float*)d_out_v;

    // ---- prep (parallel) ----
    k_embed_x<<<(B * L * INE + 255) / 256, 256, 0, stream>>>(E_sent, E_field, E_ppos, E_pneg,
                                                             value, field, ppos, pneg, x);
    k_embed_sent<<<(T * B * 400 + 255) / 256, 256, 0, stream>>>(E_sent, sent, sx);
    k_transpose<<<(460 * 1000 + 255) / 256, 256, 0, stream>>>(WihfT, enc_Wih_f, 460, 1000);
    k_transpose<<<(460 * 1000 + 255) / 256, 256, 0, stream>>>(WihbT, enc_Wih_b, 460, 1000);
    k_transpose<<<(400 * 2000 + 255) / 256, 256, 0, stream>>>(WdecT, dec_Wih, 400, 2000);
    k_pack4<<<(250 * 250 * 4 + 255) / 256, 256, 0, stream>>>(w4enc, enc_Whh_f, 250, 250);
    k_pack4<<<(250 * 250 * 4 + 255) / 256, 256, 0, stream>>>(w4enc + 250000, enc_Whh_b, 250, 250);
    k_pack4<<<(500 * 500 * 4 + 255) / 256, 256, 0, stream>>>(w4dec, dec_Whh, 500, 500);
    k_zerod<<<(16000 + 255) / 256, 256, 0, stream>>>(h_enc, 16000);   // phase 0
    k_zerod<<<(16000 + 255) / 256, 256, 0, stream>>>(c_enc, 16000);
    {
        dim3 g1(100, 4); k_gemm_xw<<<g1, 256, 0, stream>>>(xwF, x, L * INE, INE, WihfT, enc_b_f, 460, 1000);
        dim3 g2(100, 4); k_gemm_xw<<<g2, 256, 0, stream>>>(xwB, x, L * INE, INE, WihbT, enc_b_b, 460, 1000);
        dim3 g3(50, 8);  k_gemm_xw<<<g3, 256, 0, stream>>>(xwD, sx, 400, B * 400, WdecT, dec_b, 400, 2000);
    }

    // ---- encoder (sequential) ----
    for (int s = 0; s < L; ++s)
        k_enc_step<<<63, 256, 0, stream>>>(h_enc, c_enc, eoT, xwF, xwB, w4enc, s);
    k_enc_tr<<<(B * L * 500 + 255) / 256, 256, 0, stream>>>(eoB, eoT);
    k_scramble<<<63, 256, 0, stream>>>(hdec, cdec, h_enc, c_enc);

    // ---- decoder (sequential) ----
    for (int t = 0; t < T; ++t) {
        k_dec_cell<<<63, 256, 0, stream>>>(hdec, cdec, xwD, w4dec, t);
        k_dec_attn<<<32, 256, 0, stream>>>(hdec, x, eoB, sx, W_d, W_z, W_out,
                                           b_out, w_l, b_l, value,
                                           attn_ws, lam_ws, widx, outs32, t);
    }
    k_hTcT<<<63, 256, 0, stream>>>(out, hdec, cdec);

    // ---- output head ----
    {
        dim3 gg(313, 25);
        k_gemm_logits_f32<<<gg, 256, 0, stream>>>(outs32, W_lin, b_lin, out);
    }
    k_red1<<<1600, 256, 0, stream>>>(out, LS1);
    {
        dim3 gp(313, 32);
        k_plexmix<<<gp, 256, 0, stream>>>(out, attn_ws, align_prob, lam_ws, LS1);
    }
    k_final2<<<1600, 256, 0, stream>>>(out, E_target);
    k_attnpred2<<<(1600 * 300 + 255) / 256, 256, 0, stream>>>(widx, E_target, out);
}

// Round 3
// 8436.350 us; speedup vs baseline: 1.9935x; 1.9935x over previous
//
#include <hip/hip_runtime.h>

#define DI __device__ __forceinline__

constexpr int B = 32, L = 100, T = 50;
constexpr int VS = 20000;
constexpr int HR = 250, HD = 500;
constexpr int INE = 460;
constexpr int OC = 1072;   // padded Wcat columns: 500 hwd | 60 hz | 500 hWo1 | 1 hwl | pad

// ---- workspace byte offsets ----
constexpr size_t O_X      = 0;                      // x [B][L][460] f32
constexpr size_t O_SX     = 5888000;                // sent_x [T][B][400] f32
constexpr size_t O_WIHFT  = 8448000;                // enc_Wih_f^T [460][1000] f32
constexpr size_t O_WIHBT  = 10288000;
constexpr size_t O_WDECT  = 12128000;               // dec_Wih^T [400][2000] f32
constexpr size_t O_W4ENC  = 15328000;               // [2dir][250u][250k][4g] f32
constexpr size_t O_W4DEC  = 17328000;               // [500u][500k][4g] f32
constexpr size_t O_WCAT   = 21328000;               // [500][1072] f32
constexpr size_t O_XWF    = 23472000;               // [100][1000][32] f64
constexpr size_t O_XWB    = 49072000;
constexpr size_t O_XWD    = 74672000;               // [50][2000][32] f64
constexpr size_t O_EOT    = 100272000;              // enc_outT [100][500][32] f64
constexpr size_t O_EOB    = 113072000;              // enc_outB [32][100][500] f64
constexpr size_t O_E2     = 125872000;              // [32][100][500] f64
constexpr size_t O_PROJ   = 138672000;              // [50][32][1072] f64
constexpr size_t O_HENC   = 152393600;              // [2ph][2dir][250][32] f64
constexpr size_t O_CENC   = 152649600;              // [2dir][250][32] f64
constexpr size_t O_HDEC   = 152777600;              // [2ph][500][32] f64
constexpr size_t O_CDEC   = 153033600;              // [500][32] f64
constexpr size_t O_AD     = 153161600;              // a f64 [1600][100]
constexpr size_t O_ATTN   = 154441600;              // [32][50][100] f32
constexpr size_t O_EWL    = 155081600;              // [32][100] f64
constexpr size_t O_SXL    = 155107200;              // [1600] f64 (t*32+b)
constexpr size_t O_AWL    = 155120000;              // [1600] f64 (b*50+t)
constexpr size_t O_LAM    = 155132800;              // [1600] f32
constexpr size_t O_LS1    = 155139200;              // [1600] f32
constexpr size_t O_WIDX   = 155145600;              // [1600] int
constexpr size_t O_OUTS   = 155152000;              // outs f32 [1600][512]
// end 158,428,800 bytes (round-1 proved >=161.3MB usable)

// output element offsets (f32)
constexpr size_t OUT_HT  = 32000000;
constexpr size_t OUT_CT  = 32016000;
constexpr size_t OUT_AP  = 32032000;
constexpr size_t OUT_DP  = 32512000;

DI double dsig(double x) { return 1.0 / (1.0 + exp(-x)); }

// ---------------- prep kernels ----------------

__global__ void k_embed_x(const float* Es, const float* Ef, const float* Ep, const float* En,
                          const int* value, const int* field, const int* ppos, const int* pneg,
                          float* x) {
    int i = blockIdx.x * 256 + threadIdx.x;
    if (i >= B * L * INE) return;
    int j = i % INE, bl = i / INE;
    float v;
    if (j < 400)      v = Es[(size_t)value[bl] * 400 + j];
    else if (j < 450) v = Ef[(size_t)field[bl] * 50 + (j - 400)];
    else if (j < 455) v = Ep[(size_t)ppos[bl] * 5 + (j - 450)];
    else              v = En[(size_t)pneg[bl] * 5 + (j - 455)];
    x[i] = v;
}

__global__ void k_embed_sent(const float* Es, const int* sent, float* sx) {
    int i = blockIdx.x * 256 + threadIdx.x;
    if (i >= T * B * 400) return;
    int k = i % 400, tb = i / 400;
    int b = tb % B, t = tb / B;
    sx[i] = Es[(size_t)sent[b * T + t] * 400 + k];
}

__global__ void k_transpose(float* dst, const float* src, int K, int G) {
    int i = blockIdx.x * 256 + threadIdx.x;
    if (i >= K * G) return;
    int g = i % G, k = i / G;
    dst[i] = src[(size_t)g * K + k];
}

__global__ void k_pack4(float* dst, const float* src, int U, int Kh) {
    int i = blockIdx.x * 256 + threadIdx.x;
    if (i >= U * Kh * 4) return;
    int g = i & 3, rest = i >> 2;
    int k = rest % Kh, u = rest / Kh;
    dst[i] = src[((size_t)(g * U + u)) * Kh + k];
}

// Wcat[d][o]: o<500 -> W_d[d][o]; o<560 -> W_z[d][o-500]; o<1060 -> W_out[d][o-560]; o==1060 -> w_l[d]; pad 0
__global__ void k_pack_wcat(float* dst, const float* Wd, const float* Wz, const float* Wo, const float* wl) {
    int i = blockIdx.x * 256 + threadIdx.x;
    if (i >= 500 * OC) return;
    int o = i % OC, d = i / OC;
    float v = 0.f;
    if (o < 500)       v = Wd[(size_t)d * 500 + o];
    else if (o < 560)  v = Wz[(size_t)d * 60 + (o - 500)];
    else if (o < 1060) v = Wo[(size_t)d * 500 + (o - 560)];
    else if (o == 1060) v = wl[d];
    dst[i] = v;
}

__global__ void k_zerod(double* p, int n) {
    int i = blockIdx.x * 256 + threadIdx.x;
    if (i < n) p[i] = 0.0;
}

// out[t][g][b] = bias[g] + sum_k xs[b,t,k] * Wt[k][g]   (f64 accumulate)
__global__ __launch_bounds__(256) void k_gemm_xw(double* out, const float* xs, int bstride, int tstride,
                                                 const float* Wt, const float* bias, int K, int G) {
    __shared__ float xls[460 * 33];
    int t = blockIdx.x;
    int g = blockIdx.y * 256 + threadIdx.x;
    bool act = g < G;
    for (int i = threadIdx.x; i < 32 * K; i += 256) {
        int b = i / K, k = i - b * K;
        xls[k * 33 + b] = xs[(size_t)b * bstride + (size_t)t * tstride + k];
    }
    __syncthreads();
    double acc[32];
    double bs = act ? (double)bias[g] : 0.0;
#pragma unroll
    for (int b = 0; b < 32; ++b) acc[b] = bs;
    for (int k = 0; k < K; ++k) {
        double w = act ? (double)Wt[(size_t)k * G + g] : 0.0;
        const float* xr = &xls[k * 33];
#pragma unroll
        for (int b = 0; b < 32; ++b) acc[b] += w * (double)xr[b];
    }
    if (act) {
        double* op = out + ((size_t)t * G + g) * 32;
#pragma unroll
        for (int b = 0; b < 32; ++b) op[b] = acc[b];
    }
}

// ---------------- encoder (k-split x2) ----------------

__global__ __launch_bounds__(256) void k_enc_step2(double* h_enc, double* c_enc, double* eoT,
                                                   const double* xwF, const double* xwB,
                                                   const float* w4enc, int s) {
    __shared__ double pz[128][5];
    int tid = threadIdx.x;
    int half = tid >> 7, li = tid & 127;
    int gt = blockIdx.x * 128 + li;            // [0,16000)
    int dir = gt / 8000, r = gt - dir * 8000;
    int u = r >> 5, b = r & 31;
    int ph = s & 1;
    int tin = dir ? (L - 1 - s) : s;
    const float4* W4 = (const float4*)w4enc + ((size_t)(dir * 250 + u)) * 250 + half * 125;
    const double* hp = h_enc + ph * 16000 + dir * 8000 + half * 125 * 32;
    double zi = 0.0, zf = 0.0, zg = 0.0, zo = 0.0;
    for (int k = 0; k < 125; ++k) {
        double hv = hp[k * 32 + b];
        float4 w = W4[k];
        zi += (double)w.x * hv; zf += (double)w.y * hv;
        zg += (double)w.z * hv; zo += (double)w.w * hv;
    }
    if (half) { pz[li][0] = zi; pz[li][1] = zf; pz[li][2] = zg; pz[li][3] = zo; }
    __syncthreads();
    if (!half) {
        const double* xw = dir ? xwB : xwF;
        zi += pz[li][0] + xw[((size_t)tin * 1000 + 0 * HR + u) * 32 + b];
        zf += pz[li][1] + xw[((size_t)tin * 1000 + 1 * HR + u) * 32 + b];
        zg += pz[li][2] + xw[((size_t)tin * 1000 + 2 * HR + u) * 32 + b];
        zo += pz[li][3] + xw[((size_t)tin * 1000 + 3 * HR + u) * 32 + b];
        double co = c_enc[dir * 8000 + u * 32 + b];
        double cn = dsig(zf) * co + dsig(zi) * tanh(zg);
        double hn = dsig(zo) * tanh(cn);
        c_enc[dir * 8000 + u * 32 + b] = cn;
        h_enc[(ph ^ 1) * 16000 + dir * 8000 + u * 32 + b] = hn;
        eoT[((size_t)tin * 500 + dir * 250 + u) * 32 + b] = hn;
    }
}

__global__ void k_enc_tr(double* eoB, const double* eoT) {
    int i = blockIdx.x * 256 + threadIdx.x;
    if (i >= B * L * 500) return;
    int e = i % 500, bl = i / 500;
    int l = bl % 100, b = bl / 100;
    eoB[i] = eoT[((size_t)l * 500 + e) * 32 + b];
}

// replicate torch .view on [2,B,250] -> [B,500]
__global__ void k_scramble(double* hdec, double* cdec, const double* henc, const double* cenc) {
    int gt = blockIdx.x * 256 + threadIdx.x;
    if (gt >= 16000) return;
    int bb = gt / 500, j = gt - bb * 500;
    int d = gt / 8000, rem = gt - d * 8000;
    int bs = rem / 250, us = rem - bs * 250;
    hdec[j * 32 + bb] = henc[d * 8000 + us * 32 + bs];   // henc = phase 0 base
    cdec[j * 32 + bb] = cenc[d * 8000 + us * 32 + bs];
}

// ---------------- attention precomputes ----------------

// E2[b][l][e] = sum_j eoB[b][l][j] * Wo[(500+j)][e] ; E_wl[b][l] = sum_j eoB[b][l][j]*wl[500+j]
__global__ __launch_bounds__(256) void k_e2(const double* eoB, const float* Wo, const float* wl,
                                            double* E2, double* E_wl) {
    __shared__ double eo_s[500];
    int bid = blockIdx.x;              // [0,3200)
    int b = bid / 100, l = bid - b * 100;
    int tid = threadIdx.x;
    for (int j = tid; j < 500; j += 256) eo_s[j] = eoB[((size_t)b * 100 + l) * 500 + j];
    __syncthreads();
#pragma unroll 2
    for (int e = tid; e < 500; e += 256) {
        double acc = 0.0;
        for (int j = 0; j < 500; ++j)
            acc += eo_s[j] * (double)Wo[(size_t)(500 + j) * 500 + e];
        E2[((size_t)b * 100 + l) * 500 + e] = acc;
    }
    if (tid < 64) {
        double p = 0.0;
        for (int j = tid; j < 500; j += 64) p += eo_s[j] * (double)wl[500 + j];
        for (int off = 32; off > 0; off >>= 1) p += __shfl_down(p, off);
        if (tid == 0) E_wl[b * 100 + l] = p;
    }
}

// SXL[t*32+b] = sum_k sx[t][b][k] * wl[1000+k]
__global__ void k_sxl(const float* sx, const float* wl, double* SXL) {
    int i = blockIdx.x * 256 + threadIdx.x;
    if (i >= 1600) return;
    double acc = 0.0;
    for (int k = 0; k < 400; ++k) acc += (double)sx[(size_t)i * 400 + k] * (double)wl[1000 + k];
    SXL[i] = acc;
}

// ---------------- decoder ----------------

__global__ __launch_bounds__(256) void k_dec_cell2(double* hdec, double* cdec, const double* xwD,
                                                   const float* w4dec, int t) {
    __shared__ double pz[128][5];
    int tid = threadIdx.x;
    int half = tid >> 7, li = tid & 127;
    int gt = blockIdx.x * 128 + li;            // [0,16000)
    int u = gt >> 5, b = gt & 31;
    int ph = t & 1;
    const float4* W4 = (const float4*)w4dec + (size_t)u * 500 + half * 250;
    const double* hp = hdec + ph * 16000 + half * 250 * 32;
    double zi = 0.0, zf = 0.0, zg = 0.0, zo = 0.0;
    for (int k = 0; k < 250; ++k) {
        double hv = hp[k * 32 + b];
        float4 w = W4[k];
        zi += (double)w.x * hv; zf += (double)w.y * hv;
        zg += (double)w.z * hv; zo += (double)w.w * hv;
    }
    if (half) { pz[li][0] = zi; pz[li][1] = zf; pz[li][2] = zg; pz[li][3] = zo; }
    __syncthreads();
    if (!half) {
        zi += pz[li][0] + xwD[((size_t)t * 2000 + 0 * HD + u) * 32 + b];
        zf += pz[li][1] + xwD[((size_t)t * 2000 + 1 * HD + u) * 32 + b];
        zg += pz[li][2] + xwD[((size_t)t * 2000 + 2 * HD + u) * 32 + b];
        zo += pz[li][3] + xwD[((size_t)t * 2000 + 3 * HD + u) * 32 + b];
        double co = cdec[u * 32 + b];
        double cn = dsig(zf) * co + dsig(zi) * tanh(zg);
        double hn = dsig(zo) * tanh(cn);
        cdec[u * 32 + b] = cn;
        hdec[(ph ^ 1) * 16000 + u * 32 + b] = hn;
    }
}

// h-projections: PROJ[t][b][o] = sum_d h[d][b] * Wcat[d][o]
__global__ __launch_bounds__(256) void k_dec_kA(const double* hdec, const float* Wcat, double* PROJ, int t) {
    __shared__ double hL[500];
    int b = blockIdx.y;
    int o = blockIdx.x * 256 + threadIdx.x;
    int ph1 = (t & 1) ^ 1;
    for (int d = threadIdx.x; d < 500; d += 256) hL[d] = hdec[ph1 * 16000 + d * 32 + b];
    __syncthreads();
    if (o >= OC) return;
    double acc = 0.0;
    for (int d = 0; d < 500; ++d) acc += hL[d] * (double)Wcat[(size_t)d * OC + o];
    PROJ[((size_t)t * 32 + b) * OC + o] = acc;
}

// scores + dual softmax + attn/AD/widx/awl (one block per b)
__global__ __launch_bounds__(256) void k_dec_kB1(
        const double* PROJ, const double* eoB, const float* x, const double* E_wl, const int* value,
        float* attn_ws, double* AD, double* AWL, int* widx, int t) {
    int b = blockIdx.x, tid = threadIdx.x;
    int m = b * T + t;
    __shared__ double hwd_s[500], hz_s[60], sd_s[100], sz_s[100], aL[100];
    __shared__ double red[256];
    __shared__ int ri[256];
    const double* pr = PROJ + ((size_t)t * 32 + b) * OC;
    for (int k = tid; k < 500; k += 256) hwd_s[k] = pr[k];
    if (tid < 60) hz_s[tid] = pr[500 + tid];
    __syncthreads();
    int w = tid >> 6, lane = tid & 63;
    for (int l = w; l < 100; l += 4) {
        const double* er = eoB + ((size_t)b * 100 + l) * 500;
        double p = 0.0;
        for (int e = lane; e < 500; e += 64) p += hwd_s[e] * er[e];
        for (int off = 32; off > 0; off >>= 1) p += __shfl_down(p, off);
        if (lane == 0) sd_s[l] = p;
        const float* zr = x + ((size_t)b * 100 + l) * 460 + 400;
        double q = (lane < 60) ? hz_s[lane] * (double)zr[lane] : 0.0;
        for (int off = 32; off > 0; off >>= 1) q += __shfl_down(q, off);
        if (lane == 0) sz_s[l] = q;
    }
    __syncthreads();
    // dual softmax, f64
    red[tid] = (tid < 100) ? sd_s[tid] : -1e300; __syncthreads();
    for (int o = 128; o > 0; o >>= 1) { if (tid < o) red[tid] = fmax(red[tid], red[tid + o]); __syncthreads(); }
    double md = red[0]; __syncthreads();
    red[tid] = (tid < 100) ? exp(sd_s[tid] - md) : 0.0; __syncthreads();
    for (int o = 128; o > 0; o >>= 1) { if (tid < o) red[tid] += red[tid + o]; __syncthreads(); }
    double Sd = red[0]; __syncthreads();
    red[tid] = (tid < 100) ? sz_s[tid] : -1e300; __syncthreads();
    for (int o = 128; o > 0; o >>= 1) { if (tid < o) red[tid] = fmax(red[tid], red[tid + o]); __syncthreads(); }
    double mz = red[0]; __syncthreads();
    red[tid] = (tid < 100) ? exp(sz_s[tid] - mz) : 0.0; __syncthreads();
    for (int o = 128; o > 0; o >>= 1) { if (tid < o) red[tid] += red[tid + o]; __syncthreads(); }
    double Sz = red[0]; __syncthreads();
    if (tid < 100) aL[tid] = (exp(sd_s[tid] - md) / Sd) * (exp(sz_s[tid] - mz) / Sz);
    __syncthreads();
    red[tid] = (tid < 100) ? aL[tid] : 0.0; __syncthreads();
    for (int o = 128; o > 0; o >>= 1) { if (tid < o) red[tid] += red[tid + o]; __syncthreads(); }
    double Sa = red[0]; __syncthreads();
    if (tid < 100) {
        double av = aL[tid] / (Sa + 1e-3);
        aL[tid] = av;
        attn_ws[(size_t)m * 100 + tid] = (float)av;
        AD[(size_t)m * 100 + tid] = av;
    }
    __syncthreads();
    // argmax (first-max) -> widx
    red[tid] = (tid < 100) ? aL[tid] : -1e300;
    ri[tid]  = (tid < 100) ? tid : 0x7fffffff;
    __syncthreads();
    for (int o = 128; o > 0; o >>= 1) {
        if (tid < o) {
            if (red[tid + o] > red[tid] || (red[tid + o] == red[tid] && ri[tid + o] < ri[tid])) {
                red[tid] = red[tid + o]; ri[tid] = ri[tid + o];
            }
        }
        __syncthreads();
    }
    if (tid == 0) widx[m] = value[b * 100 + ri[0]];
    // awl = a . E_wl[b]
    if (tid < 64) {
        double p = (tid < 100) ? aL[tid] * E_wl[b * 100 + tid] : 0.0;
        if (tid + 64 < 100) p += aL[tid + 64] * E_wl[b * 100 + tid + 64];
        for (int off = 32; off > 0; off >>= 1) p += __shfl_down(p, off);
        if (tid == 0) AWL[m] = p;
    }
}

// post-loop: outs[m][e] = tanh(hWo1 + a@E2 + b_out); lam[m] = sigmoid(hwl + awl + sxl + b_l)
__global__ __launch_bounds__(256) void k_outs(const double* PROJ, const double* AD, const double* E2,
                                              const double* AWL, const double* SXL,
                                              const float* b_out, const float* b_l,
                                              float* outs32, float* lam_ws) {
    __shared__ double ad_s[100];
    int m = blockIdx.x, tid = threadIdx.x;
    int b = m / T, t = m - b * T;
    if (tid < 100) ad_s[tid] = AD[(size_t)m * 100 + tid];
    __syncthreads();
    const double* pr = PROJ + ((size_t)t * 32 + b) * OC;
#pragma unroll 2
    for (int e = tid; e < 512; e += 256) {
        if (e < 500) {
            double acc = pr[560 + e] + (double)b_out[e];
            const double* e2 = E2 + (size_t)b * 50000 + e;
            for (int l = 0; l < 100; ++l) acc += ad_s[l] * e2[l * 500];
            outs32[(size_t)m * 512 + e] = (float)tanh(acc);
        } else {
            outs32[(size_t)m * 512 + e] = 0.f;
        }
    }
    if (tid == 0)
        lam_ws[m] = (float)dsig(pr[1060] + AWL[m] + SXL[t * 32 + b] + (double)b_l[0]);
}

__global__ void k_hTcT(float* out, const double* hdec, const double* cdec) {
    int i = blockIdx.x * 256 + threadIdx.x;
    if (i >= 16000) return;
    int b = i / 500, u = i - b * 500;
    out[OUT_HT + i] = (float)hdec[u * 32 + b];   // phase-0 base holds h_T
    out[OUT_CT + i] = (float)cdec[u * 32 + b];
}

// ---------------- logits GEMM (f32 vector): d_out = outs @ W_lin^T + b_lin ----------------

__global__ __launch_bounds__(256) void k_gemm_logits_f32(const float* outs32, const float* W_lin,
                                                         const float* b_lin, float* d_out) {
    __shared__ float As[16][68], Bs[16][68];
    int n0 = blockIdx.x * 64, m0 = blockIdx.y * 64;
    int tid = threadIdx.x;
    int ty = tid >> 4, tx = tid & 15;
    int lr = tid >> 2, lc = tid & 3;
    float acc[4][4];
#pragma unroll
    for (int i = 0; i < 4; ++i)
#pragma unroll
        for (int j = 0; j < 4; ++j) acc[i][j] = 0.f;

    for (int k0 = 0; k0 < 512; k0 += 16) {
        int k4 = k0 + lc * 4;
        float4 av = *(const float4*)(outs32 + (size_t)(m0 + lr) * 512 + k4);
        int n = n0 + lr;
        float4 bv;
        if (n < VS && k4 < 500) bv = *(const float4*)(W_lin + (size_t)n * 500 + k4);
        else bv = make_float4(0.f, 0.f, 0.f, 0.f);
        __syncthreads();
        As[lc * 4 + 0][lr] = av.x; As[lc * 4 + 1][lr] = av.y;
        As[lc * 4 + 2][lr] = av.z; As[lc * 4 + 3][lr] = av.w;
        Bs[lc * 4 + 0][lr] = bv.x; Bs[lc * 4 + 1][lr] = bv.y;
        Bs[lc * 4 + 2][lr] = bv.z; Bs[lc * 4 + 3][lr] = bv.w;
        __syncthreads();
#pragma unroll
        for (int kk = 0; kk < 16; ++kk) {
            float4 a4 = *(const float4*)&As[kk][ty * 4];
            float4 b4 = *(const float4*)&Bs[kk][tx * 4];
            float ar[4] = {a4.x, a4.y, a4.z, a4.w};
            float br[4] = {b4.x, b4.y, b4.z, b4.w};
#pragma unroll
            for (int i = 0; i < 4; ++i)
#pragma unroll
                for (int j = 0; j < 4; ++j) acc[i][j] += ar[i] * br[j];
        }
    }
#pragma unroll
    for (int j = 0; j < 4; ++j) {
        int n = n0 + tx * 4 + j;
        if (n < VS) {
            float bl = b_lin[n];
#pragma unroll
            for (int i = 0; i < 4; ++i) {
                int mm = m0 + ty * 4 + i;
                d_out[(size_t)mm * VS + n] = acc[i][j] + bl;
            }
        }
    }
}

// ---------------- softmax passes ----------------

__global__ void k_red1(const float* d_out, float* LS1) {
    int m = blockIdx.x, tid = threadIdx.x;
    const float* row = d_out + (size_t)m * VS;
    __shared__ float red[256];
    float lm = -3e38f;
    for (int v = tid; v < VS; v += 256) lm = fmaxf(lm, row[v]);
    red[tid] = lm; __syncthreads();
    for (int o = 128; o > 0; o >>= 1) { if (tid < o) red[tid] = fmaxf(red[tid], red[tid + o]); __syncthreads(); }
    float m1 = red[0]; __syncthreads();
    float ls = 0.f;
    for (int v = tid; v < VS; v += 256) ls += expf(row[v] - m1);
    red[tid] = ls; __syncthreads();
    for (int o = 128; o > 0; o >>= 1) { if (tid < o) red[tid] += red[tid + o]; __syncthreads(); }
    if (tid == 0) LS1[m] = m1 + logf(red[0]);
}

__global__ __launch_bounds__(256) void k_plexmix(float* d_out, const float* attn_ws, const float* align_prob,
                                                 const float* lam_ws, const float* LS1) {
    int b = blockIdx.y, v0 = blockIdx.x * 64, tid = threadIdx.x;
    __shared__ float attn_s[50 * 100];
    __shared__ float al[100 * 64];
    for (int i = tid; i < 5000; i += 256) attn_s[i] = attn_ws[(size_t)b * 5000 + i];
    for (int i = tid; i < 6400; i += 256) {
        int l = i >> 6, j = i & 63;
        int v = v0 + j;
        al[i] = (v < VS) ? align_prob[((size_t)b * 100 + l) * VS + v] : 0.f;
    }
    __syncthreads();
    for (int idx = tid; idx < 50 * 64; idx += 256) {
        int t = idx >> 6, j = idx & 63;
        int v = v0 + j;
        if (v < VS) {
            float acc = 0.f;
            for (int l = 0; l < 100; ++l) acc += attn_s[t * 100 + l] * al[l * 64 + j];
            int m = b * T + t;
            size_t p = (size_t)m * VS + v;
            float lamv = lam_ws[m];
            d_out[p] = lamv * acc + (1.f - lamv) * (d_out[p] - LS1[m]);
        }
    }
}

__global__ void k_final2(float* d_out, const float* E_target) {
    int m = blockIdx.x, tid = threadIdx.x;
    float* row = d_out + (size_t)m * VS;
    __shared__ float sm[256], ss[256], sbv[256];
    __shared__ int sbi[256];
    float rm = -3e38f, rs = 0.f, bv = -3e38f; int bi = 0;
    for (int v = tid; v < VS; v += 256) {
        float xv = row[v];
        if (xv > bv) { bv = xv; bi = v; }
        if (xv > rm) { rs = rs * expf(rm - xv) + 1.f; rm = xv; }
        else rs += expf(xv - rm);
    }
    sm[tid] = rm; ss[tid] = rs; sbv[tid] = bv; sbi[tid] = bi;
    __syncthreads();
    for (int o = 128; o > 0; o >>= 1) {
        if (tid < o) {
            float m1 = sm[tid], m2 = sm[tid + o];
            float M = fmaxf(m1, m2);
            ss[tid] = ss[tid] * expf(m1 - M) + ss[tid + o] * expf(m2 - M);
            sm[tid] = M;
            if (sbv[tid + o] > sbv[tid] || (sbv[tid + o] == sbv[tid] && sbi[tid + o] < sbi[tid])) {
                sbv[tid] = sbv[tid + o]; sbi[tid] = sbi[tid + o];
            }
        }
        __syncthreads();
    }
    float ls2 = sm[0] + logf(ss[0]);
    int amax = sbi[0];
    for (int v = tid; v < VS; v += 256) row[v] -= ls2;
    for (int j = tid; j < 300; j += 256)
        d_out[OUT_DP + (size_t)m * 300 + j] = E_target[(size_t)amax * 300 + j];
}

__global__ void k_attnpred2(const int* widx, const float* E_target, float* d_out) {
    int i = blockIdx.x * 256 + threadIdx.x;
    if (i >= 1600 * 300) return;
    int m = i / 300, j = i - m * 300;
    d_out[OUT_AP + i] = E_target[(size_t)widx[m] * 300 + j];
}

// ---------------- launch ----------------

extern "C" void kernel_launch(void* const* d_in, const int* in_sizes, int n_in,
                              void* d_out_v, int out_size, void* d_ws, size_t ws_size,
                              hipStream_t stream) {
    const float* align_prob = (const float*)d_in[1];
    const float* E_sent     = (const float*)d_in[2];
    const float* E_field    = (const float*)d_in[3];
    const float* E_ppos     = (const float*)d_in[4];
    const float* E_pneg     = (const float*)d_in[5];
    const float* E_target   = (const float*)d_in[6];
    const float* enc_Wih_f  = (const float*)d_in[7];
    const float* enc_Whh_f  = (const float*)d_in[8];
    const float* enc_b_f    = (const float*)d_in[9];
    const float* enc_Wih_b  = (const float*)d_in[10];
    const float* enc_Whh_b  = (const float*)d_in[11];
    const float* enc_b_b    = (const float*)d_in[12];
    const float* dec_Wih    = (const float*)d_in[13];
    const float* dec_Whh    = (const float*)d_in[14];
    const float* dec_b      = (const float*)d_in[15];
    const float* W_d        = (const float*)d_in[16];
    const float* W_z        = (const float*)d_in[17];
    const float* W_out      = (const float*)d_in[18];
    const float* b_out      = (const float*)d_in[19];
    const float* w_l        = (const float*)d_in[20];
    const float* b_l        = (const float*)d_in[21];
    const float* W_lin      = (const float*)d_in[22];
    const float* b_lin      = (const float*)d_in[23];
    const int* sent  = (const int*)d_in[24];
    const int* value = (const int*)d_in[25];
    const int* field = (const int*)d_in[26];
    const int* ppos  = (const int*)d_in[27];
    const int* pneg  = (const int*)d_in[28];

    char* ws = (char*)d_ws;
    float*  x      = (float*)(ws + O_X);
    float*  sx     = (float*)(ws + O_SX);
    float*  WihfT  = (float*)(ws + O_WIHFT);
    float*  WihbT  = (float*)(ws + O_WIHBT);
    float*  WdecT  = (float*)(ws + O_WDECT);
    float*  w4enc  = (float*)(ws + O_W4ENC);
    float*  w4dec  = (float*)(ws + O_W4DEC);
    float*  Wcat   = (float*)(ws + O_WCAT);
    double* xwF    = (double*)(ws + O_XWF);
    double* xwB    = (double*)(ws + O_XWB);
    double* xwD    = (double*)(ws + O_XWD);
    double* eoT    = (double*)(ws + O_EOT);
    double* eoB    = (double*)(ws + O_EOB);
    double* E2     = (double*)(ws + O_E2);
    double* PROJ   = (double*)(ws + O_PROJ);
    double* h_enc  = (double*)(ws + O_HENC);
    double* c_enc  = (double*)(ws + O_CENC);
    double* hdec   = (double*)(ws + O_HDEC);
    double* cdec   = (double*)(ws + O_CDEC);
    double* AD     = (double*)(ws + O_AD);
    float*  attn_ws= (float*)(ws + O_ATTN);
    double* E_wl   = (double*)(ws + O_EWL);
    double* SXL    = (double*)(ws + O_SXL);
    double* AWL    = (double*)(ws + O_AWL);
    float*  lam_ws = (float*)(ws + O_LAM);
    float*  LS1    = (float*)(ws + O_LS1);
    int*    widx   = (int*)(ws + O_WIDX);
    float*  outs32 = (float*)(ws + O_OUTS);
    float* out = (float*)d_out_v;

    // ---- prep (parallel) ----
    k_embed_x<<<(B * L * INE + 255) / 256, 256, 0, stream>>>(E_sent, E_field, E_ppos, E_pneg,
                                                             value, field, ppos, pneg, x);
    k_embed_sent<<<(T * B * 400 + 255) / 256, 256, 0, stream>>>(E_sent, sent, sx);
    k_transpose<<<(460 * 1000 + 255) / 256, 256, 0, stream>>>(WihfT, enc_Wih_f, 460, 1000);
    k_transpose<<<(460 * 1000 + 255) / 256, 256, 0, stream>>>(WihbT, enc_Wih_b, 460, 1000);
    k_transpose<<<(400 * 2000 + 255) / 256, 256, 0, stream>>>(WdecT, dec_Wih, 400, 2000);
    k_pack4<<<(250 * 250 * 4 + 255) / 256, 256, 0, stream>>>(w4enc, enc_Whh_f, 250, 250);
    k_pack4<<<(250 * 250 * 4 + 255) / 256, 256, 0, stream>>>(w4enc + 250000, enc_Whh_b, 250, 250);
    k_pack4<<<(500 * 500 * 4 + 255) / 256, 256, 0, stream>>>(w4dec, dec_Whh, 500, 500);
    k_pack_wcat<<<(500 * OC + 255) / 256, 256, 0, stream>>>(Wcat, W_d, W_z, W_out, w_l);
    k_zerod<<<(16000 + 255) / 256, 256, 0, stream>>>(h_enc, 16000);   // phase 0
    k_zerod<<<(16000 + 255) / 256, 256, 0, stream>>>(c_enc, 16000);
    k_sxl<<<(1600 + 255) / 256, 256, 0, stream>>>(sx, w_l, SXL);
    {
        dim3 g1(100, 4); k_gemm_xw<<<g1, 256, 0, stream>>>(xwF, x, L * INE, INE, WihfT, enc_b_f, 460, 1000);
        dim3 g2(100, 4); k_gemm_xw<<<g2, 256, 0, stream>>>(xwB, x, L * INE, INE, WihbT, enc_b_b, 460, 1000);
        dim3 g3(50, 8);  k_gemm_xw<<<g3, 256, 0, stream>>>(xwD, sx, 400, B * 400, WdecT, dec_b, 400, 2000);
    }

    // ---- encoder (sequential) ----
    for (int s = 0; s < L; ++s)
        k_enc_step2<<<125, 256, 0, stream>>>(h_enc, c_enc, eoT, xwF, xwB, w4enc, s);
    k_enc_tr<<<(B * L * 500 + 255) / 256, 256, 0, stream>>>(eoB, eoT);
    k_scramble<<<63, 256, 0, stream>>>(hdec, cdec, h_enc, c_enc);
    k_e2<<<3200, 256, 0, stream>>>(eoB, W_out, w_l, E2, E_wl);

    // ---- decoder (sequential) ----
    for (int t = 0; t < T; ++t) {
        k_dec_cell2<<<125, 256, 0, stream>>>(hdec, cdec, xwD, w4dec, t);
        {
            dim3 ga((OC + 255) / 256, 32);
            k_dec_kA<<<ga, 256, 0, stream>>>(hdec, Wcat, PROJ, t);
        }
        k_dec_kB1<<<32, 256, 0, stream>>>(PROJ, eoB, x, E_wl, value, attn_ws, AD, AWL, widx, t);
    }
    k_hTcT<<<63, 256, 0, stream>>>(out, hdec, cdec);
    k_outs<<<1600, 256, 0, stream>>>(PROJ, AD, E2, AWL, SXL, b_out, b_l, outs32, lam_ws);

    // ---- output head ----
    {
        dim3 gg(313, 25);
        k_gemm_logits_f32<<<gg, 256, 0, stream>>>(outs32, W_lin, b_lin, out);
    }
    k_red1<<<1600, 256, 0, stream>>>(out, LS1);
    {
        dim3 gp(313, 32);
        k_plexmix<<<gp, 256, 0, stream>>>(out, attn_ws, align_prob, lam_ws, LS1);
    }
    k_final2<<<1600, 256, 0, stream>>>(out, E_target);
    k_attnpred2<<<(1600 * 300 + 255) / 256, 256, 0, stream>>>(widx, E_target, out);
}